// Round 6
// baseline (189.263 us; speedup 1.0000x reference)
//
#include <hip/hip_runtime.h>
#include <math.h>

#define SIG_L 128000
#define NBATCH 64
#define NROWS 257
#define HOP 128
#define NUMF 999
#define NFRM 30
#define NWIN 969
#define NB_MAX 16
#define FBINS 160          // kmap entries (>= 144 used bins)
#define TILES 9            // M = 288 rows = 144 bins x (re,im)
#define KSTEPS 16
#define FPB 128            // frames per block
#define BETA_F 6.623413251903491f  // 1 + 10^(15/20)

typedef __attribute__((ext_vector_type(8))) short short8;
typedef __attribute__((ext_vector_type(16))) float f32x16;
typedef unsigned short ushort_t;

// RNE split of fp32 into bf16 hi + bf16 lo (hi RNE; rem = v - hi exact in fp32)
__device__ inline ushort_t bf_hi_rne(float v, float* rem) {
    unsigned u = __float_as_uint(v);
    unsigned hr = (u + 0x7FFFu + ((u >> 16) & 1u)) & 0xFFFF0000u;
    *rem = v - __uint_as_float(hr);
    return (ushort_t)(hr >> 16);
}
__device__ inline ushort_t bf_rne(float v) {
    unsigned u = __float_as_uint(v);
    return (ushort_t)((u + 0x7FFFu + ((u >> 16) & 1u)) >> 16);
}

// ---------- K0: octmat scan -> hdr[32+f] = band id of bin f (or -1) ----------
__global__ void k_scan(const float* __restrict__ oct, int NB, int* __restrict__ hdr) {
    __shared__ int smin[16], smax[16];
    int tid = threadIdx.x;
    if (tid < NB) { smin[tid] = 0x7fffffff; smax[tid] = -1; }
    __syncthreads();
    for (int idx = tid; idx < NB * NROWS; idx += blockDim.x) {
        int k = idx / NROWS, f = idx % NROWS;
        if (oct[idx] != 0.0f) { atomicMin(&smin[k], f); atomicMax(&smax[k], f); }
    }
    __syncthreads();
    if (tid < FBINS) {
        int kid = -1;
        for (int k = 0; k < NB; ++k)
            if (smax[k] >= 0 && tid >= smin[k] && tid <= smax[k]) kid = k;
        hdr[32 + tid] = kid;
    }
}

// ---------- K0b: weight pack, fragment order, kk-chunked ----------
// wpack[((kk*9 + t)*2 + p)*512 + l*8 + e]  (shorts); p: 0=hi 1=lo
// A-frag semantics: lane l holds A[row32 = l&31][k = kk*16 + (l>>5)*8 + e]
// row32 = 2m+part -> bin = t*16 + m, part: 0=re 1=im
__global__ void k_prep(const float* __restrict__ fftmat, ushort_t* __restrict__ wpack) {
    for (int u = 0; u < 2; ++u) {
        int idx = blockIdx.x * 512 + u * 256 + threadIdx.x;   // < 147456
        int e = idx & 7, l = (idx >> 3) & 63, p = (idx >> 9) & 1;
        int tt = (idx >> 10) % TILES, kk = (idx >> 10) / TILES;
        int row32 = l & 31, kq = l >> 5;
        int bin = tt * 16 + (row32 >> 1);
        int part = row32 & 1;
        int k = kk * 16 + kq * 8 + e;
        float v = fftmat[(size_t)(part ? (NROWS + bin) : bin) * 512 + 128 + k];
        float rem; ushort_t hb = bf_hi_rne(v, &rem);
        wpack[idx] = p ? bf_rne(rem) : hb;
    }
}

// ---------- K1 helpers ----------
// B LDS planes hold frag-ordered bf16: Bh[((bt*2+kq)*32 + jloc)*8 + e]
// A comes straight from global (wpack is in fragment order; wave load = 1024B coalesced, L2-hot)
template <int MT>
__device__ __attribute__((always_inline)) void compute_step(
    const ushort_t* __restrict__ wpack, int kk,
    const short* __restrict__ Bhb, const short* __restrict__ Blb,
    int tbase, int fh, int lane, f32x16* acc) {
    const int jloc = lane & 31, kq = lane >> 5;
    short8 Sh[2], Sl[2];
#pragma unroll
    for (int bt = 0; bt < 2; ++bt) {
        const int bb = (((fh * 2 + bt) * 2 + kq) * 32 + jloc) * 8;
        Sh[bt] = *(const short8*)&Bhb[bb];
        Sl[bt] = *(const short8*)&Blb[bb];
    }
    const ushort_t* ab = wpack + (size_t)(kk * TILES + tbase) * 1024 + lane * 8;
#pragma unroll
    for (int g = 0; g < MT; ++g) {
        short8 Ah = *(const short8*)(ab + g * 1024);
        short8 Al = *(const short8*)(ab + g * 1024 + 512);
        acc[g*2+0] = __builtin_amdgcn_mfma_f32_32x32x16_bf16(Ah, Sh[0], acc[g*2+0], 0, 0, 0);
        acc[g*2+1] = __builtin_amdgcn_mfma_f32_32x32x16_bf16(Ah, Sh[1], acc[g*2+1], 0, 0, 0);
        acc[g*2+0] = __builtin_amdgcn_mfma_f32_32x32x16_bf16(Ah, Sl[0], acc[g*2+0], 0, 0, 0);
        acc[g*2+1] = __builtin_amdgcn_mfma_f32_32x32x16_bf16(Ah, Sl[1], acc[g*2+1], 0, 0, 0);
        acc[g*2+0] = __builtin_amdgcn_mfma_f32_32x32x16_bf16(Al, Sh[0], acc[g*2+0], 0, 0, 0);
        acc[g*2+1] = __builtin_amdgcn_mfma_f32_32x32x16_bf16(Al, Sh[1], acc[g*2+1], 0, 0, 0);
    }
}

template <int MT>
__device__ __attribute__((always_inline)) void epilogue_bands(
    const f32x16* acc, const int* kmapS, float* bacc, int tbase, int fh, int lane) {
    const int jloc = lane & 31, kq = lane >> 5;
#pragma unroll
    for (int g = 0; g < MT; ++g) {
#pragma unroll
        for (int bt = 0; bt < 2; ++bt) {
            const int fl = fh * 64 + bt * 32 + jloc;
            float run = 0.0f; int runk = -1;
#pragma unroll
            for (int rr = 0; rr < 8; ++rr) {
                const int r = rr * 2;
                const int m = ((r & 2) >> 1) + 4 * (r >> 2) + 2 * kq;
                const int kid = kmapS[(tbase + g) * 16 + m];
                const float vr = acc[g*2+bt][r], vi = acc[g*2+bt][r+1];
                const float e = vr * vr + vi * vi;
                if (kid != runk) {
                    if (runk >= 0) atomicAdd(&bacc[runk * FPB + fl], run);
                    run = 0.0f; runk = kid;
                }
                if (kid >= 0) run += e;
            }
            if (runk >= 0) atomicAdd(&bacc[runk * FPB + fl], run);
        }
    }
}

// ---------- K1: MFMA STFT energies + band reduce (A from L2, B LDS-dbuf) ----------
// grid (8, NBATCH, 2), block 256. z=0: targ->xbuf, z=1: pred->ybuf. Stores band ENERGIES.
__global__ __launch_bounds__(256, 1) void k_stft(
    const float* __restrict__ targ, const float* __restrict__ pred,
    const ushort_t* __restrict__ wpack, const int* __restrict__ hdr,
    float* __restrict__ xbuf, float* __restrict__ ybuf, int NB) {
    __shared__ short Bh[2][2048];           // 8192 B  (frag-ordered bf16 hi)
    __shared__ short Bl[2][2048];           // 8192 B  (lo)
    __shared__ float bacc[NB_MAX * FPB];    // 8192 B
    __shared__ int kmapS[FBINS];            // 640 B   -> total ~25 KB

    const int tid = threadIdx.x;
    const int lane = tid & 63;
    const int wv = __builtin_amdgcn_readfirstlane(tid >> 6);
    const int mh = wv >> 1;                 // M-half: 0 -> tiles 0..4, 1 -> tiles 5..8
    const int fh = wv & 1;                  // frame-half
    const int b = blockIdx.y, z = blockIdx.z;
    const int t0 = blockIdx.x * FPB;
    const float* __restrict__ sig = z ? pred : targ;
    float* __restrict__ out = z ? ybuf : xbuf;
    const size_t boff = (size_t)b * SIG_L;

    for (int i = tid; i < NB_MAX * FPB; i += 256) bacc[i] = 0.0f;
    for (int i = tid; i < FBINS; i += 256) kmapS[i] = hdr[32 + i];

    // B-stage geometry: fl = tid>>1 (frame 0..127), kq = tid&1
    const int s_fl = tid >> 1, s_kq = tid & 1;
    const int s_bt = s_fl >> 5, s_jl = s_fl & 31;
    const int s_dst = (((s_fl >> 6) * 0 + s_bt) * 2 + s_kq) * 32 * 8 + s_jl * 8; // ((bt*2+kq)*32+jl)*8
    const bool s_val = (t0 + s_fl) < NUMF;
    const float* s_src = sig + boff + (size_t)(t0 + s_fl) * HOP + s_kq * 8;

    f32x16 acc[10];
#pragma unroll
    for (int m = 0; m < 10; ++m)
#pragma unroll
        for (int e = 0; e < 16; ++e) acc[m][e] = 0.0f;

    // ---- prologue: stage B kk=0 into buf 0 ----
    {
        float4 x0 = {0,0,0,0}, x1 = {0,0,0,0};
        if (s_val) { x0 = *(const float4*)(s_src); x1 = *(const float4*)(s_src + 4); }
        float s8[8] = {x0.x, x0.y, x0.z, x0.w, x1.x, x1.y, x1.z, x1.w};
        short8 vh, vl;
#pragma unroll
        for (int e = 0; e < 8; ++e) {
            float rem;
            vh[e] = (short)bf_hi_rne(s8[e], &rem);
            vl[e] = (short)bf_rne(rem);
        }
        *(short8*)&Bh[0][s_dst] = vh;
        *(short8*)&Bl[0][s_dst] = vl;
    }

    int cur = 0;
#pragma unroll 1
    for (int kk = 0; kk < KSTEPS; ++kk) {
        __syncthreads();                         // Bs[cur] ready
        const int nxt = cur ^ 1;
        const bool doSt = (kk < KSTEPS - 1);
        float4 x0 = {0,0,0,0}, x1 = {0,0,0,0};
        if (doSt && s_val) {                     // issue-early signal loads for kk+1
            const float* p = s_src + (kk + 1) * 16;
            x0 = *(const float4*)(p); x1 = *(const float4*)(p + 4);
        }
        if (mh == 0) compute_step<5>(wpack, kk, &Bh[cur][0], &Bl[cur][0], 0, fh, lane, acc);
        else         compute_step<4>(wpack, kk, &Bh[cur][0], &Bl[cur][0], 5, fh, lane, acc);
        if (doSt) {                              // write-late: convert + store B(kk+1)
            float s8[8] = {x0.x, x0.y, x0.z, x0.w, x1.x, x1.y, x1.z, x1.w};
            short8 vh, vl;
#pragma unroll
            for (int e = 0; e < 8; ++e) {
                float rem;
                vh[e] = (short)bf_hi_rne(s8[e], &rem);
                vl[e] = (short)bf_rne(rem);
            }
            *(short8*)&Bh[nxt][s_dst] = vh;
            *(short8*)&Bl[nxt][s_dst] = vl;
        }
        cur = nxt;
    }

    // ---- epilogue: energies -> band accumulate -> global ----
    if (mh == 0) epilogue_bands<5>(acc, kmapS, bacc, 0, fh, lane);
    else         epilogue_bands<4>(acc, kmapS, bacc, 5, fh, lane);
    __syncthreads();
    for (int idx = tid; idx < NB * FPB; idx += 256) {
        int k = idx >> 7, t = idx & (FPB - 1);
        int tg = t0 + t;
        if (tg < NUMF)
            out[((size_t)b * NB + k) * NUMF + tg] = bacc[k * FPB + t];
    }
}

// ---------- K2: sliding-window correlations (reads energies, applies sqrt) ----------
__global__ __launch_bounds__(256) void k_corr(const float* __restrict__ xbuf,
                                              const float* __restrict__ ybuf,
                                              int NB, double* __restrict__ partials) {
    const int k = blockIdx.x, b = blockIdx.y;
    const long roff = ((long)b * NB + k) * NUMF;
    __shared__ float xl[NUMF], yl[NUMF];
    __shared__ double red[256];
    const int tid = threadIdx.x;
    for (int i = tid; i < NUMF; i += 256) {
        xl[i] = sqrtf(xbuf[roff + i]);
        yl[i] = sqrtf(ybuf[roff + i]);
    }
    __syncthreads();
    double loc = 0.0;
    for (int w = tid; w < NWIN; w += 256) {
        float sx = 0, sxx = 0, syy = 0;
        for (int i = 0; i < NFRM; ++i) {
            float xv = xl[w + i], yv = yl[w + i];
            sx += xv; sxx += xv * xv; syy += yv * yv;
        }
        float alpha = sqrtf(sxx / (syy + 1e-7f));
        float sy = 0;
        for (int i = 0; i < NFRM; ++i)
            sy += fminf(alpha * yl[w + i], BETA_F * xl[w + i]);
        float mx = sx * (1.0f / NFRM), my = sy * (1.0f / NFRM);
        float cxx = 0, cyy = 0, cxy = 0;
        for (int i = 0; i < NFRM; ++i) {
            float dx = xl[w + i] - mx;
            float dy = fminf(alpha * yl[w + i], BETA_F * xl[w + i]) - my;
            cxx += dx * dx; cyy += dy * dy; cxy += dx * dy;
        }
        loc += (double)cxy / sqrt((double)cxx * (double)cyy);
    }
    red[tid] = loc;
    __syncthreads();
    for (int s = 128; s > 0; s >>= 1) {
        if (tid < s) red[tid] += red[tid + s];
        __syncthreads();
    }
    if (tid == 0) partials[b * NB + k] = red[0];
}

// ---------- K3: final deterministic reduction ----------
__global__ void k_final(const double* __restrict__ partials, int NB, float* __restrict__ out) {
    __shared__ double red[256];
    const int tid = threadIdx.x;
    const int n = NBATCH * NB;
    double s = 0.0;
    for (int i = tid; i < n; i += 256) s += partials[i];
    red[tid] = s;
    __syncthreads();
    for (int st = 128; st > 0; st >>= 1) {
        if (tid < st) red[tid] += red[tid + st];
        __syncthreads();
    }
    if (tid == 0) out[0] = (float)(-red[0] / ((double)NBATCH * NB * NWIN));
}

extern "C" void kernel_launch(void* const* d_in, const int* in_sizes, int n_in,
                              void* d_out, int out_size, void* d_ws, size_t ws_size,
                              hipStream_t stream) {
    const float* pred   = (const float*)d_in[0];
    const float* targ   = (const float*)d_in[1];
    const float* fftmat = (const float*)d_in[3];
    const float* oct    = (const float*)d_in[4];
    const int NB = in_sizes[4] / NROWS;   // 15

    char* ws = (char*)d_ws;
    int*      hdr   = (int*)ws;                          // 1 KB
    ushort_t* wpack = (ushort_t*)(ws + 1024);            // 147456 shorts = 294912 B
    size_t o1 = 1024 + (size_t)KSTEPS * TILES * 2 * 512 * 2;
    size_t xsz = (size_t)NBATCH * NB_MAX * NUMF * 4;
    float*  xbuf = (float*)(ws + o1);
    float*  ybuf = (float*)(ws + o1 + xsz);
    double* partials = (double*)(ws + o1 + 2 * xsz);

    hipLaunchKernelGGL(k_scan, dim3(1), dim3(256), 0, stream, oct, NB, hdr);
    hipLaunchKernelGGL(k_prep, dim3(288), dim3(256), 0, stream, fftmat, wpack);
    hipLaunchKernelGGL(k_stft, dim3(8, NBATCH, 2), dim3(256), 0, stream,
                       targ, pred, wpack, hdr, xbuf, ybuf, NB);
    hipLaunchKernelGGL(k_corr, dim3(NB, NBATCH), dim3(256), 0, stream, xbuf, ybuf, NB, partials);
    hipLaunchKernelGGL(k_final, dim3(1), dim3(256), 0, stream, partials, NB, (float*)d_out);
}

// Round 7
// 127.238 us; speedup vs baseline: 1.4875x; 1.4875x over previous
//
#include <hip/hip_runtime.h>
#include <math.h>

#define SIG_L 128000
#define NBATCH 64
#define NROWS 257
#define HOP 128
#define NUMF 999
#define NFRM 30
#define NWIN 969
#define NB_MAX 16
#define FBINS 160          // kmap entries (>= 144 used bins)
#define TILES 9            // M = 288 rows = 144 bins x (re,im)
#define KSTEPS 16
#define FPB 64             // frames per block
#define NT 16              // ceil(999/64)
#define BETA_F 6.623413251903491f  // 1 + 10^(15/20)

typedef __attribute__((ext_vector_type(4))) short short4_t;
typedef __attribute__((ext_vector_type(8))) short short8;
typedef __attribute__((ext_vector_type(16))) float f32x16;
typedef unsigned short ushort_t;

// RNE split of fp32 into bf16 hi + bf16 lo (hi RNE; rem = v - hi exact in fp32)
__device__ inline ushort_t bf_hi_rne(float v, float* rem) {
    unsigned u = __float_as_uint(v);
    unsigned hr = (u + 0x7FFFu + ((u >> 16) & 1u)) & 0xFFFF0000u;
    *rem = v - __uint_as_float(hr);
    return (ushort_t)(hr >> 16);
}
__device__ inline ushort_t bf_rne(float v) {
    unsigned u = __float_as_uint(v);
    return (ushort_t)((u + 0x7FFFu + ((u >> 16) & 1u)) >> 16);
}

// ---------- K0: octmat scan -> hdr[32+f] = band id of bin f (or -1) ----------
__global__ void k_scan(const float* __restrict__ oct, int NB, int* __restrict__ hdr) {
    __shared__ int smin[16], smax[16];
    int tid = threadIdx.x;
    if (tid < NB) { smin[tid] = 0x7fffffff; smax[tid] = -1; }
    __syncthreads();
    for (int idx = tid; idx < NB * NROWS; idx += blockDim.x) {
        int k = idx / NROWS, f = idx % NROWS;
        if (oct[idx] != 0.0f) { atomicMin(&smin[k], f); atomicMax(&smax[k], f); }
    }
    __syncthreads();
    if (tid < FBINS) {
        int kid = -1;
        for (int k = 0; k < NB; ++k)
            if (smax[k] >= 0 && tid >= smin[k] && tid <= smax[k]) kid = k;
        hdr[32 + tid] = kid;
    }
}

// ---------- K0b: weight pack, fragment order, kk-chunked ----------
// wpack[((kk*9 + t)*2 + p)*512 + l*8 + e]  (shorts); p: 0=hi 1=lo
// A-frag semantics: lane l holds A[row32 = l&31][k = kk*16 + (l>>5)*8 + e]
// row32 = 2m+part -> bin = t*16 + m, part: 0=re 1=im
__global__ void k_prep(const float* __restrict__ fftmat, ushort_t* __restrict__ wpack) {
    for (int u = 0; u < 2; ++u) {
        int idx = blockIdx.x * 512 + u * 256 + threadIdx.x;   // < 147456
        int e = idx & 7, l = (idx >> 3) & 63, p = (idx >> 9) & 1;
        int tt = (idx >> 10) % TILES, kk = (idx >> 10) / TILES;
        int row32 = l & 31, kq = l >> 5;
        int bin = tt * 16 + (row32 >> 1);
        int part = row32 & 1;
        int k = kk * 16 + kq * 8 + e;
        float v = fftmat[(size_t)(part ? (NROWS + bin) : bin) * 512 + 128 + k];
        float rem; ushort_t hb = bf_hi_rne(v, &rem);
        wpack[idx] = p ? bf_rne(rem) : hb;
    }
}

// ---------- K1 helpers ----------
// B LDS planes, frag order: Bh[((fh*2+kq)*32 + jloc)*8 + e]  (1024 shorts per buf)
// A direct from global: wpack is fragment-ordered; wave load = 1024B coalesced, L2-hot
template <int MT>
__device__ __attribute__((always_inline)) void compute_step(
    const ushort_t* __restrict__ wpack, int kk,
    const short* __restrict__ Bhb, const short* __restrict__ Blb,
    int tbase, int fh, int lane, f32x16* acc) {
    const int jloc = lane & 31, kq = lane >> 5;
    const int bb = ((fh * 2 + kq) * 32 + jloc) * 8;
    short8 Sh = *(const short8*)&Bhb[bb];
    short8 Sl = *(const short8*)&Blb[bb];
    const ushort_t* ab = wpack + (size_t)(kk * TILES + tbase) * 1024 + lane * 8;
#pragma unroll
    for (int g = 0; g < MT; ++g) {
        short8 Ah = *(const short8*)(ab + g * 1024);
        short8 Al = *(const short8*)(ab + g * 1024 + 512);
        acc[g] = __builtin_amdgcn_mfma_f32_32x32x16_bf16(Ah, Sh, acc[g], 0, 0, 0);
        acc[g] = __builtin_amdgcn_mfma_f32_32x32x16_bf16(Ah, Sl, acc[g], 0, 0, 0);
        acc[g] = __builtin_amdgcn_mfma_f32_32x32x16_bf16(Al, Sh, acc[g], 0, 0, 0);
    }
}

template <int MT>
__device__ __attribute__((always_inline)) void epilogue_bands(
    const f32x16* acc, const int* kmapS, float* bacc, int tbase, int fh, int lane) {
    const int jloc = lane & 31, kq = lane >> 5;
    const int fl = fh * 32 + jloc;
#pragma unroll
    for (int g = 0; g < MT; ++g) {
        float run = 0.0f; int runk = -1;
#pragma unroll
        for (int rr = 0; rr < 8; ++rr) {
            const int r = rr * 2;
            const int m = ((r & 2) >> 1) + 4 * (r >> 2) + 2 * kq;
            const int kid = kmapS[(tbase + g) * 16 + m];
            const float vr = acc[g][r], vi = acc[g][r + 1];
            const float e = vr * vr + vi * vi;
            if (kid != runk) {
                if (runk >= 0) atomicAdd(&bacc[runk * FPB + fl], run);
                run = 0.0f; runk = kid;
            }
            if (kid >= 0) run += e;
        }
        if (runk >= 0) atomicAdd(&bacc[runk * FPB + fl], run);
    }
}

// ---------- K1: MFMA STFT energies + band reduce (A from L2, B LDS-dbuf) ----------
// grid (NT, NBATCH, 2), block 256. z=0: targ->xbuf, z=1: pred->ybuf. Stores band ENERGIES.
__global__ __launch_bounds__(256, 2) void k_stft(
    const float* __restrict__ targ, const float* __restrict__ pred,
    const ushort_t* __restrict__ wpack, const int* __restrict__ hdr,
    float* __restrict__ xbuf, float* __restrict__ ybuf, int NB) {
    __shared__ short Bh[2][1024];           // 4096 B (frag-ordered bf16 hi)
    __shared__ short Bl[2][1024];           // 4096 B (lo)
    __shared__ float bacc[NB_MAX * FPB];    // 4096 B
    __shared__ int kmapS[FBINS];            // 640 B  -> ~13 KB total

    const int tid = threadIdx.x;
    const int lane = tid & 63;
    const int wv = __builtin_amdgcn_readfirstlane(tid >> 6);
    const int mh = wv >> 1;                 // M-half: 0 -> tiles 0..4, 1 -> tiles 5..8
    const int fh = wv & 1;                  // frame-half (one 32-frame B tile each)
    const int b = blockIdx.y, z = blockIdx.z;
    const int t0 = blockIdx.x * FPB;
    const float* __restrict__ sig = z ? pred : targ;
    float* __restrict__ out = z ? ybuf : xbuf;
    const size_t boff = (size_t)b * SIG_L;

    for (int i = tid; i < NB_MAX * FPB; i += 256) bacc[i] = 0.0f;
    for (int i = tid; i < FBINS; i += 256) kmapS[i] = hdr[32 + i];

    // B-stage geometry: one float4 per thread per kk.
    // tid -> g = tid>>1 (frag group), h = tid&1 (which half of the 8 samples)
    // g -> fl = g>>1 (frame 0..63), kq = g&1
    const int s_g = tid >> 1, s_h = tid & 1;
    const int s_fl = s_g >> 1, s_kq = s_g & 1;
    const int s_dst = (((s_fl >> 5) * 2 + s_kq) * 32 + (s_fl & 31)) * 8 + s_h * 4;
    const bool s_val = (t0 + s_fl) < NUMF;
    const float* s_src = sig + boff + (size_t)(t0 + s_fl) * HOP + s_kq * 8 + s_h * 4;

    f32x16 acc[5];
#pragma unroll
    for (int m = 0; m < 5; ++m)
#pragma unroll
        for (int e = 0; e < 16; ++e) acc[m][e] = 0.0f;

    // ---- prologue: stage B kk=0 into buf 0 ----
    {
        float4 x = {0, 0, 0, 0};
        if (s_val) x = *(const float4*)(s_src);
        float s4[4] = {x.x, x.y, x.z, x.w};
        short4_t vh, vl;
#pragma unroll
        for (int e = 0; e < 4; ++e) {
            float rem;
            vh[e] = (short)bf_hi_rne(s4[e], &rem);
            vl[e] = (short)bf_rne(rem);
        }
        *(short4_t*)&Bh[0][s_dst] = vh;
        *(short4_t*)&Bl[0][s_dst] = vl;
    }

    int cur = 0;
#pragma unroll 1
    for (int kk = 0; kk < KSTEPS; ++kk) {
        __syncthreads();                         // B[cur] ready
        const int nxt = cur ^ 1;
        const bool doSt = (kk < KSTEPS - 1);
        float4 x = {0, 0, 0, 0};
        if (doSt && s_val)                       // issue-early signal load for kk+1
            x = *(const float4*)(s_src + (kk + 1) * 16);
        if (mh == 0) compute_step<5>(wpack, kk, &Bh[cur][0], &Bl[cur][0], 0, fh, lane, acc);
        else         compute_step<4>(wpack, kk, &Bh[cur][0], &Bl[cur][0], 5, fh, lane, acc);
        if (doSt) {                              // write-late: convert + store B(kk+1)
            float s4[4] = {x.x, x.y, x.z, x.w};
            short4_t vh, vl;
#pragma unroll
            for (int e = 0; e < 4; ++e) {
                float rem;
                vh[e] = (short)bf_hi_rne(s4[e], &rem);
                vl[e] = (short)bf_rne(rem);
            }
            *(short4_t*)&Bh[nxt][s_dst] = vh;
            *(short4_t*)&Bl[nxt][s_dst] = vl;
        }
        cur = nxt;
    }

    // ---- epilogue: energies -> band accumulate -> global ----
    if (mh == 0) epilogue_bands<5>(acc, kmapS, bacc, 0, fh, lane);
    else         epilogue_bands<4>(acc, kmapS, bacc, 5, fh, lane);
    __syncthreads();
    for (int idx = tid; idx < NB * FPB; idx += 256) {
        int k = idx >> 6, t = idx & (FPB - 1);
        int tg = t0 + t;
        if (tg < NUMF)
            out[((size_t)b * NB + k) * NUMF + tg] = bacc[k * FPB + t];
    }
}

// ---------- K2: sliding-window correlations (reads energies, applies sqrt) ----------
__global__ __launch_bounds__(256) void k_corr(const float* __restrict__ xbuf,
                                              const float* __restrict__ ybuf,
                                              int NB, double* __restrict__ partials) {
    const int k = blockIdx.x, b = blockIdx.y;
    const long roff = ((long)b * NB + k) * NUMF;
    __shared__ float xl[NUMF], yl[NUMF];
    __shared__ double red[256];
    const int tid = threadIdx.x;
    for (int i = tid; i < NUMF; i += 256) {
        xl[i] = sqrtf(xbuf[roff + i]);
        yl[i] = sqrtf(ybuf[roff + i]);
    }
    __syncthreads();
    double loc = 0.0;
    for (int w = tid; w < NWIN; w += 256) {
        float sx = 0, sxx = 0, syy = 0;
        for (int i = 0; i < NFRM; ++i) {
            float xv = xl[w + i], yv = yl[w + i];
            sx += xv; sxx += xv * xv; syy += yv * yv;
        }
        float alpha = sqrtf(sxx / (syy + 1e-7f));
        float sy = 0;
        for (int i = 0; i < NFRM; ++i)
            sy += fminf(alpha * yl[w + i], BETA_F * xl[w + i]);
        float mx = sx * (1.0f / NFRM), my = sy * (1.0f / NFRM);
        float cxx = 0, cyy = 0, cxy = 0;
        for (int i = 0; i < NFRM; ++i) {
            float dx = xl[w + i] - mx;
            float dy = fminf(alpha * yl[w + i], BETA_F * xl[w + i]) - my;
            cxx += dx * dx; cyy += dy * dy; cxy += dx * dy;
        }
        loc += (double)cxy / sqrt((double)cxx * (double)cyy);
    }
    red[tid] = loc;
    __syncthreads();
    for (int s = 128; s > 0; s >>= 1) {
        if (tid < s) red[tid] += red[tid + s];
        __syncthreads();
    }
    if (tid == 0) partials[b * NB + k] = red[0];
}

// ---------- K3: final deterministic reduction ----------
__global__ void k_final(const double* __restrict__ partials, int NB, float* __restrict__ out) {
    __shared__ double red[256];
    const int tid = threadIdx.x;
    const int n = NBATCH * NB;
    double s = 0.0;
    for (int i = tid; i < n; i += 256) s += partials[i];
    red[tid] = s;
    __syncthreads();
    for (int st = 128; st > 0; st >>= 1) {
        if (tid < st) red[tid] += red[tid + st];
        __syncthreads();
    }
    if (tid == 0) out[0] = (float)(-red[0] / ((double)NBATCH * NB * NWIN));
}

extern "C" void kernel_launch(void* const* d_in, const int* in_sizes, int n_in,
                              void* d_out, int out_size, void* d_ws, size_t ws_size,
                              hipStream_t stream) {
    const float* pred   = (const float*)d_in[0];
    const float* targ   = (const float*)d_in[1];
    const float* fftmat = (const float*)d_in[3];
    const float* oct    = (const float*)d_in[4];
    const int NB = in_sizes[4] / NROWS;   // 15

    char* ws = (char*)d_ws;
    int*      hdr   = (int*)ws;                          // 1 KB
    ushort_t* wpack = (ushort_t*)(ws + 1024);            // 147456 shorts = 294912 B
    size_t o1 = 1024 + (size_t)KSTEPS * TILES * 2 * 512 * 2;
    size_t xsz = (size_t)NBATCH * NB_MAX * NUMF * 4;
    float*  xbuf = (float*)(ws + o1);
    float*  ybuf = (float*)(ws + o1 + xsz);
    double* partials = (double*)(ws + o1 + 2 * xsz);

    hipLaunchKernelGGL(k_scan, dim3(1), dim3(256), 0, stream, oct, NB, hdr);
    hipLaunchKernelGGL(k_prep, dim3(288), dim3(256), 0, stream, fftmat, wpack);
    hipLaunchKernelGGL(k_stft, dim3(NT, NBATCH, 2), dim3(256), 0, stream,
                       targ, pred, wpack, hdr, xbuf, ybuf, NB);
    hipLaunchKernelGGL(k_corr, dim3(NB, NBATCH), dim3(256), 0, stream, xbuf, ybuf, NB, partials);
    hipLaunchKernelGGL(k_final, dim3(1), dim3(256), 0, stream, partials, NB, (float*)d_out);
}

// Round 8
// 127.120 us; speedup vs baseline: 1.4889x; 1.0009x over previous
//
#include <hip/hip_runtime.h>
#include <math.h>

#define SIG_L 128000
#define NBATCH 64
#define NROWS 257
#define HOP 128
#define NUMF 999
#define NFRM 30
#define NWIN 969
#define NB_MAX 16
#define FBINS 160          // kmap entries (>= 144 used bins)
#define TILES 9            // M = 288 rows = 144 bins x (re,im)
#define KSTEPS 16
#define FPB 64             // frames per block
#define NT 16              // ceil(999/64)
#define BETA_F 6.623413251903491f  // 1 + 10^(15/20)

typedef __attribute__((ext_vector_type(4))) short short4_t;
typedef __attribute__((ext_vector_type(8))) short short8;
typedef __attribute__((ext_vector_type(16))) float f32x16;
typedef unsigned short ushort_t;

// RNE split of fp32 into bf16 hi + bf16 lo (hi RNE; rem = v - hi exact in fp32)
__device__ inline ushort_t bf_hi_rne(float v, float* rem) {
    unsigned u = __float_as_uint(v);
    unsigned hr = (u + 0x7FFFu + ((u >> 16) & 1u)) & 0xFFFF0000u;
    *rem = v - __uint_as_float(hr);
    return (ushort_t)(hr >> 16);
}
__device__ inline ushort_t bf_rne(float v) {
    unsigned u = __float_as_uint(v);
    return (ushort_t)((u + 0x7FFFu + ((u >> 16) & 1u)) >> 16);
}

// ---------- K0: octmat scan -> hdr[32+f] = band id of bin f (or -1) ----------
__global__ void k_scan(const float* __restrict__ oct, int NB, int* __restrict__ hdr) {
    __shared__ int smin[16], smax[16];
    int tid = threadIdx.x;
    if (tid < NB) { smin[tid] = 0x7fffffff; smax[tid] = -1; }
    __syncthreads();
    for (int idx = tid; idx < NB * NROWS; idx += blockDim.x) {
        int k = idx / NROWS, f = idx % NROWS;
        if (oct[idx] != 0.0f) { atomicMin(&smin[k], f); atomicMax(&smax[k], f); }
    }
    __syncthreads();
    if (tid < FBINS) {
        int kid = -1;
        for (int k = 0; k < NB; ++k)
            if (smax[k] >= 0 && tid >= smin[k] && tid <= smax[k]) kid = k;
        hdr[32 + tid] = kid;
    }
}

// ---------- K0b: weight pack, fragment order, kk-chunked ----------
// wpack[((kk*9 + t)*2 + p)*512 + l*8 + e]  (shorts); p: 0=hi 1=lo
// A-frag: lane l holds A[row32 = l&31][k = kk*16 + (l>>5)*8 + e]
// row32 = 2m+part -> bin = t*16 + m, part: 0=re 1=im
__global__ void k_prep(const float* __restrict__ fftmat, ushort_t* __restrict__ wpack) {
    for (int u = 0; u < 2; ++u) {
        int idx = blockIdx.x * 512 + u * 256 + threadIdx.x;   // < 147456
        int e = idx & 7, l = (idx >> 3) & 63, p = (idx >> 9) & 1;
        int tt = (idx >> 10) % TILES, kk = (idx >> 10) / TILES;
        int row32 = l & 31, kq = l >> 5;
        int bin = tt * 16 + (row32 >> 1);
        int part = row32 & 1;
        int k = kk * 16 + kq * 8 + e;
        float v = fftmat[(size_t)(part ? (NROWS + bin) : bin) * 512 + 128 + k];
        float rem; ushort_t hb = bf_hi_rne(v, &rem);
        wpack[idx] = p ? bf_rne(rem) : hb;
    }
}

// ---------- K1 helpers ----------
template <int MT>
__device__ __attribute__((always_inline)) void load_a(
    const ushort_t* __restrict__ wpack, int kk, int tbase, int lane,
    short8* Ah, short8* Al) {
    const ushort_t* ab = wpack + (size_t)(kk * TILES + tbase) * 1024 + lane * 8;
#pragma unroll
    for (int g = 0; g < MT; ++g) {
        Ah[g] = *(const short8*)(ab + g * 1024);
        Al[g] = *(const short8*)(ab + g * 1024 + 512);
    }
}

template <int MT>
__device__ __attribute__((always_inline)) void mfma_block(
    const short8* Ah, const short8* Al, short8 Sh, short8 Sl, f32x16* acc) {
#pragma unroll
    for (int g = 0; g < MT; ++g) {
        acc[g] = __builtin_amdgcn_mfma_f32_32x32x16_bf16(Ah[g], Sh, acc[g], 0, 0, 0);
        acc[g] = __builtin_amdgcn_mfma_f32_32x32x16_bf16(Ah[g], Sl, acc[g], 0, 0, 0);
        acc[g] = __builtin_amdgcn_mfma_f32_32x32x16_bf16(Al[g], Sh, acc[g], 0, 0, 0);
    }
}

__device__ __attribute__((always_inline)) void cvt_store_b(
    float4 x, short* BhS, short* BlS, int dst) {
    float s4[4] = {x.x, x.y, x.z, x.w};
    short4_t vh, vl;
#pragma unroll
    for (int e = 0; e < 4; ++e) {
        float rem;
        vh[e] = (short)bf_hi_rne(s4[e], &rem);
        vl[e] = (short)bf_rne(rem);
    }
    *(short4_t*)&BhS[dst] = vh;
    *(short4_t*)&BlS[dst] = vl;
}

template <int MT>
__device__ __attribute__((always_inline)) void epilogue_bands(
    const f32x16* acc, const int* kmapS, float* bacc, int tbase, int fh, int lane) {
    const int jloc = lane & 31, kq = lane >> 5;
    const int fl = fh * 32 + jloc;
#pragma unroll
    for (int g = 0; g < MT; ++g) {
        float run = 0.0f; int runk = -1;
#pragma unroll
        for (int rr = 0; rr < 8; ++rr) {
            const int r = rr * 2;
            const int m = ((r & 2) >> 1) + 4 * (r >> 2) + 2 * kq;
            const int kid = kmapS[(tbase + g) * 16 + m];
            const float vr = acc[g][r], vi = acc[g][r + 1];
            const float e = vr * vr + vi * vi;
            if (kid != runk) {
                if (runk >= 0) atomicAdd(&bacc[runk * FPB + fl], run);
                run = 0.0f; runk = kid;
            }
            if (kid >= 0) run += e;
        }
        if (runk >= 0) atomicAdd(&bacc[runk * FPB + fl], run);
    }
}

// ---------- K1: MFMA STFT energies + band reduce ----------
// A: direct from L2 (fragment-ordered wpack), register double-buffered 1 kk ahead.
// B: LDS, staged in kk-PAIRS (8 barriers), issue-early/write-late.
// grid (NT, NBATCH, 2), block 256. Stores band ENERGIES (sqrt in k_corr).
__global__ __launch_bounds__(256, 2) void k_stft(
    const float* __restrict__ targ, const float* __restrict__ pred,
    const ushort_t* __restrict__ wpack, const int* __restrict__ hdr,
    float* __restrict__ xbuf, float* __restrict__ ybuf, int NB) {
    __shared__ short Bh[4][1024];           // [buf*2+slot] 8192 B
    __shared__ short Bl[4][1024];           // 8192 B
    __shared__ float bacc[NB_MAX * FPB];    // 4096 B
    __shared__ int kmapS[FBINS];            // 640 B

    const int tid = threadIdx.x;
    const int lane = tid & 63;
    const int wv = __builtin_amdgcn_readfirstlane(tid >> 6);
    const int mh = wv >> 1;                 // M-half: 0 -> tiles 0..4, 1 -> tiles 5..8
    const int fh = wv & 1;                  // frame-half (one 32-frame B tile)
    const int tbase = mh ? 5 : 0;
    const int b = blockIdx.y, z = blockIdx.z;
    const int t0 = blockIdx.x * FPB;
    const float* __restrict__ sig = z ? pred : targ;
    float* __restrict__ out = z ? ybuf : xbuf;
    const size_t boff = (size_t)b * SIG_L;

    for (int i = tid; i < NB_MAX * FPB; i += 256) bacc[i] = 0.0f;
    for (int i = tid; i < FBINS; i += 256) kmapS[i] = hdr[32 + i];

    // B-stage geometry: one float4 per thread per kk
    const int s_g = tid >> 1, s_h = tid & 1;
    const int s_fl = s_g >> 1, s_kq = s_g & 1;
    const int s_dst = (((s_fl >> 5) * 2 + s_kq) * 32 + (s_fl & 31)) * 8 + s_h * 4;
    const bool s_val = (t0 + s_fl) < NUMF;
    const float* s_src = sig + boff + (size_t)(t0 + s_fl) * HOP + s_kq * 8 + s_h * 4;

    f32x16 acc[5];
#pragma unroll
    for (int m = 0; m < 5; ++m)
#pragma unroll
        for (int e = 0; e < 16; ++e) acc[m][e] = 0.0f;

    short8 A0h[5], A0l[5], A1h[5], A1l[5];

    // ---- prologue: stage B kk=0,1 into buf0 slots 0,1; load A for kk=0 ----
    {
        float4 x0 = {0,0,0,0}, x1 = {0,0,0,0};
        if (s_val) { x0 = *(const float4*)(s_src); x1 = *(const float4*)(s_src + 16); }
        cvt_store_b(x0, &Bh[0][0], &Bl[0][0], s_dst);
        cvt_store_b(x1, &Bh[1][0], &Bl[1][0], s_dst);
    }
    if (mh == 0) load_a<5>(wpack, 0, 0, lane, A0h, A0l);
    else         load_a<4>(wpack, 0, 5, lane, A0h, A0l);

    const int bb = ((fh * 2 + (lane >> 5)) * 32 + (lane & 31)) * 8;

    int cur = 0;
#pragma unroll 1
    for (int s = 0; s < 8; ++s) {
        const int kk2 = 2 * s;
        __syncthreads();                     // B[cur] pair ready
        const int nxt = cur ^ 1;
        const bool doSt = (s < 7);
        // issue-early: B global loads for kk2+2, kk2+3
        float4 x0 = {0,0,0,0}, x1 = {0,0,0,0};
        if (doSt && s_val) {
            x0 = *(const float4*)(s_src + (kk2 + 2) * 16);
            x1 = *(const float4*)(s_src + (kk2 + 3) * 16);
        }
        // B fragments for both slots (available since barrier)
        short8 S0h = *(const short8*)&Bh[cur * 2 + 0][bb];
        short8 S0l = *(const short8*)&Bl[cur * 2 + 0][bb];
        short8 S1h = *(const short8*)&Bh[cur * 2 + 1][bb];
        short8 S1l = *(const short8*)&Bl[cur * 2 + 1][bb];
        // even half-step: prefetch A(kk2+1) -> A1, compute with A0
        if (mh == 0) { load_a<5>(wpack, kk2 + 1, 0, lane, A1h, A1l);
                       mfma_block<5>(A0h, A0l, S0h, S0l, acc); }
        else         { load_a<4>(wpack, kk2 + 1, 5, lane, A1h, A1l);
                       mfma_block<4>(A0h, A0l, S0h, S0l, acc); }
        // odd half-step: prefetch A(kk2+2) -> A0, compute with A1
        if (doSt) {
            if (mh == 0) load_a<5>(wpack, kk2 + 2, 0, lane, A0h, A0l);
            else         load_a<4>(wpack, kk2 + 2, 5, lane, A0h, A0l);
        }
        if (mh == 0) mfma_block<5>(A1h, A1l, S1h, S1l, acc);
        else         mfma_block<4>(A1h, A1l, S1h, S1l, acc);
        // write-late: convert + store B pair for next super-step
        if (doSt) {
            cvt_store_b(x0, &Bh[nxt * 2 + 0][0], &Bl[nxt * 2 + 0][0], s_dst);
            cvt_store_b(x1, &Bh[nxt * 2 + 1][0], &Bl[nxt * 2 + 1][0], s_dst);
        }
        cur = nxt;
    }

    // ---- epilogue: energies -> band accumulate -> global ----
    if (mh == 0) epilogue_bands<5>(acc, kmapS, bacc, 0, fh, lane);
    else         epilogue_bands<4>(acc, kmapS, bacc, 5, fh, lane);
    __syncthreads();
    for (int idx = tid; idx < NB * FPB; idx += 256) {
        int k = idx >> 6, t = idx & (FPB - 1);
        int tg = t0 + t;
        if (tg < NUMF)
            out[((size_t)b * NB + k) * NUMF + tg] = bacc[k * FPB + t];
    }
}

// ---------- K2: sliding-window correlations (reads energies, applies sqrt) ----------
__global__ __launch_bounds__(256) void k_corr(const float* __restrict__ xbuf,
                                              const float* __restrict__ ybuf,
                                              int NB, double* __restrict__ partials) {
    const int k = blockIdx.x, b = blockIdx.y;
    const long roff = ((long)b * NB + k) * NUMF;
    __shared__ float xl[NUMF], yl[NUMF];
    __shared__ double red[256];
    const int tid = threadIdx.x;
    for (int i = tid; i < NUMF; i += 256) {
        xl[i] = sqrtf(xbuf[roff + i]);
        yl[i] = sqrtf(ybuf[roff + i]);
    }
    __syncthreads();
    double loc = 0.0;
    for (int w = tid; w < NWIN; w += 256) {
        float sx = 0, sxx = 0, syy = 0;
        for (int i = 0; i < NFRM; ++i) {
            float xv = xl[w + i], yv = yl[w + i];
            sx += xv; sxx += xv * xv; syy += yv * yv;
        }
        float alpha = sqrtf(sxx / (syy + 1e-7f));
        float sy = 0;
        for (int i = 0; i < NFRM; ++i)
            sy += fminf(alpha * yl[w + i], BETA_F * xl[w + i]);
        float mx = sx * (1.0f / NFRM), my = sy * (1.0f / NFRM);
        float cxx = 0, cyy = 0, cxy = 0;
        for (int i = 0; i < NFRM; ++i) {
            float dx = xl[w + i] - mx;
            float dy = fminf(alpha * yl[w + i], BETA_F * xl[w + i]) - my;
            cxx += dx * dx; cyy += dy * dy; cxy += dx * dy;
        }
        loc += (double)cxy / sqrt((double)cxx * (double)cyy);
    }
    red[tid] = loc;
    __syncthreads();
    for (int s = 128; s > 0; s >>= 1) {
        if (tid < s) red[tid] += red[tid + s];
        __syncthreads();
    }
    if (tid == 0) partials[b * NB + k] = red[0];
}

// ---------- K3: final deterministic reduction ----------
__global__ void k_final(const double* __restrict__ partials, int NB, float* __restrict__ out) {
    __shared__ double red[256];
    const int tid = threadIdx.x;
    const int n = NBATCH * NB;
    double s = 0.0;
    for (int i = tid; i < n; i += 256) s += partials[i];
    red[tid] = s;
    __syncthreads();
    for (int st = 128; st > 0; st >>= 1) {
        if (tid < st) red[tid] += red[tid + st];
        __syncthreads();
    }
    if (tid == 0) out[0] = (float)(-red[0] / ((double)NBATCH * NB * NWIN));
}

extern "C" void kernel_launch(void* const* d_in, const int* in_sizes, int n_in,
                              void* d_out, int out_size, void* d_ws, size_t ws_size,
                              hipStream_t stream) {
    const float* pred   = (const float*)d_in[0];
    const float* targ   = (const float*)d_in[1];
    const float* fftmat = (const float*)d_in[3];
    const float* oct    = (const float*)d_in[4];
    const int NB = in_sizes[4] / NROWS;   // 15

    char* ws = (char*)d_ws;
    int*      hdr   = (int*)ws;                          // 1 KB
    ushort_t* wpack = (ushort_t*)(ws + 1024);            // 147456 shorts = 294912 B
    size_t o1 = 1024 + (size_t)KSTEPS * TILES * 2 * 512 * 2;
    size_t xsz = (size_t)NBATCH * NB_MAX * NUMF * 4;
    float*  xbuf = (float*)(ws + o1);
    float*  ybuf = (float*)(ws + o1 + xsz);
    double* partials = (double*)(ws + o1 + 2 * xsz);

    hipLaunchKernelGGL(k_scan, dim3(1), dim3(256), 0, stream, oct, NB, hdr);
    hipLaunchKernelGGL(k_prep, dim3(288), dim3(256), 0, stream, fftmat, wpack);
    hipLaunchKernelGGL(k_stft, dim3(NT, NBATCH, 2), dim3(256), 0, stream,
                       targ, pred, wpack, hdr, xbuf, ybuf, NB);
    hipLaunchKernelGGL(k_corr, dim3(NB, NBATCH), dim3(256), 0, stream, xbuf, ybuf, NB, partials);
    hipLaunchKernelGGL(k_final, dim3(1), dim3(256), 0, stream, partials, NB, (float*)d_out);
}